// Round 1
// baseline (167.769 us; speedup 1.0000x reference)
//
#include <hip/hip_runtime.h>
#include <stdint.h>

typedef unsigned short u16;
typedef short bf8 __attribute__((ext_vector_type(8)));   // 8 bf16 (bit pattern)
typedef float f4 __attribute__((ext_vector_type(4)));

#define TTOK 8192
#define HD   1024
#define NE   8

static __device__ __forceinline__ u16 f2bf(float f) {
  union { float f; uint32_t u; } v; v.f = f;
  return (u16)((v.u + 0x7fffu + ((v.u >> 16) & 1u)) >> 16);   // RNE
}

// ---------------- gating (fp32) + x -> bf16 conversion ----------------
__global__ __launch_bounds__(256) void gate_conv_kernel(
    const float* __restrict__ x, const float* __restrict__ gw,
    const float* __restrict__ gb, float* __restrict__ wout,
    u16* __restrict__ abf)
{
  const int t    = blockIdx.x * 4 + (threadIdx.x >> 6);
  const int lane = threadIdx.x & 63;
  const float* xr = x + (size_t)t * HD;
  float p[NE];
#pragma unroll
  for (int e = 0; e < NE; ++e) p[e] = 0.f;
#pragma unroll 4
  for (int h = lane; h < HD; h += 64) {
    const float xv = xr[h];
    abf[(size_t)t * HD + h] = f2bf(xv);
    const float* g = gw + (size_t)h * NE;
#pragma unroll
    for (int e = 0; e < NE; ++e) p[e] += xv * g[e];
  }
#pragma unroll
  for (int e = 0; e < NE; ++e) {
#pragma unroll
    for (int off = 32; off > 0; off >>= 1)
      p[e] += __shfl_xor(p[e], off, 64);
    p[e] += gb[e];
  }
  float m = p[0];
#pragma unroll
  for (int e = 1; e < NE; ++e) m = fmaxf(m, p[e]);
  float s = 0.f;
#pragma unroll
  for (int e = 0; e < NE; ++e) { p[e] = expf(p[e] - m); s += p[e]; }
  const float inv = 1.f / s;
  if (lane == 0) {
#pragma unroll
    for (int e = 0; e < NE; ++e) wout[t * NE + e] = p[e] * inv;
  }
}

// ------------- expert_w [E][H][H] fp32 -> Wt [E][d][h] bf16 (transposed) -------------
__global__ __launch_bounds__(256) void wconv_kernel(
    const float* __restrict__ ew, u16* __restrict__ wt)
{
  __shared__ u16 tile[64][66];   // +2 pad breaks transpose bank conflicts
  const int e  = blockIdx.z;
  const int h0 = blockIdx.y * 64;
  const int d0 = blockIdx.x * 64;
  const int c  = threadIdx.x & 63;
  const int r0 = threadIdx.x >> 6;
  const float* src = ew + (size_t)e * HD * HD;
  u16* dst = wt + (size_t)e * HD * HD;
#pragma unroll
  for (int i = 0; i < 16; ++i) {
    const int r = i * 4 + r0;
    tile[r][c] = f2bf(src[(size_t)(h0 + r) * HD + d0 + c]);
  }
  __syncthreads();
#pragma unroll
  for (int i = 0; i < 16; ++i) {
    const int r = i * 4 + r0;
    dst[(size_t)(d0 + r) * HD + h0 + c] = tile[c][r];
  }
}

// ---------------- fused dense-MoE GEMM ----------------
// out[t,d] = sum_e w[t,e] * ( sum_k A[t,k] * Wt[e][d][k] + eb[e][d] )
#define BM 128
#define BN 128
#define BK 64

__global__ __launch_bounds__(256, 2) void moe_gemm_kernel(
    const u16* __restrict__ A,      // [T][H] bf16
    const u16* __restrict__ Wt,     // [E][H(d)][H(k)] bf16
    const float* __restrict__ wg,   // [T][E]
    const float* __restrict__ eb,   // [E][H]
    float* __restrict__ out)        // [T][H] fp32
{
  __shared__ u16 As[BM * BK];       // swizzled-linear: slot(r,g') holds global granule g'^(r&7)
  __shared__ u16 Bs[BN * BK];

  const int bid   = blockIdx.x;
  // XCD-chunked swizzle (512 % 8 == 0, bijective): xcd gets contiguous bm chunk
  const int local = bid >> 3;
  const int bm    = (bid & 7) * 8 + (local & 7);
  const int bn    = local >> 3;

  const int tid  = threadIdx.x;
  const int lane = tid & 63;
  const int wid  = tid >> 6;
  const int wr   = wid >> 1;
  const int wc   = wid & 1;
  const int l15  = lane & 15;
  const int lhi  = lane >> 4;

  const int row0 = bm * BM;
  const int col0 = bn * BN;

  const f4 fz = {0.f, 0.f, 0.f, 0.f};
  f4 accO[4][4];
#pragma unroll
  for (int i = 0; i < 4; ++i)
#pragma unroll
    for (int j = 0; j < 4; ++j) accO[i][j] = fz;

  for (int e = 0; e < NE; ++e) {
    const u16* Bsrc = Wt + (size_t)e * HD * HD;
    f4 acc[4][4];
#pragma unroll
    for (int i = 0; i < 4; ++i)
#pragma unroll
      for (int j = 0; j < 4; ++j) acc[i][j] = fz;

    for (int kt = 0; kt < HD / BK; ++kt) {
      const int kcol = kt * BK;
      // stage A (16KB) + B (16KB); LDS dest linear, source pre-swizzled (G21)
#pragma unroll
      for (int j = 0; j < 4; ++j) {
        const int lin = j * 4096 + tid * 16;
        const int r   = lin >> 7;              // 128B per row (BK*2)
        const int gsw = ((lin >> 4) & 7) ^ (r & 7);
        __builtin_amdgcn_global_load_lds(
            (const __attribute__((address_space(1))) void*)(A + (size_t)(row0 + r) * HD + kcol + gsw * 8),
            (__attribute__((address_space(3))) void*)((char*)As + lin),
            16, 0, 0);
        __builtin_amdgcn_global_load_lds(
            (const __attribute__((address_space(1))) void*)(Bsrc + (size_t)(col0 + r) * HD + kcol + gsw * 8),
            (__attribute__((address_space(3))) void*)((char*)Bs + lin),
            16, 0, 0);
      }
      __syncthreads();   // compiler drains vmcnt(0) before s_barrier

#pragma unroll
      for (int kk = 0; kk < 2; ++kk) {
        bf8 af[4], bfr[4];
#pragma unroll
        for (int mi = 0; mi < 4; ++mi) {
          const int ar = wr * 64 + mi * 16 + l15;
          const int g  = kk * 4 + lhi;
          af[mi] = *(const bf8*)((const char*)As + ar * 128 + ((g ^ (ar & 7)) << 4));
        }
#pragma unroll
        for (int ni = 0; ni < 4; ++ni) {
          const int br = wc * 64 + ni * 16 + l15;
          const int g  = kk * 4 + lhi;
          bfr[ni] = *(const bf8*)((const char*)Bs + br * 128 + ((g ^ (br & 7)) << 4));
        }
#pragma unroll
        for (int mi = 0; mi < 4; ++mi)
#pragma unroll
          for (int ni = 0; ni < 4; ++ni)
            acc[mi][ni] = __builtin_amdgcn_mfma_f32_16x16x32_bf16(af[mi], bfr[ni], acc[mi][ni], 0, 0, 0);
      }
      __syncthreads();
    }

    // fold this expert into output accumulator with per-row gate weight
#pragma unroll
    for (int mi = 0; mi < 4; ++mi) {
      const int tb = row0 + wr * 64 + mi * 16 + lhi * 4;   // C/D: row=(lane>>4)*4+reg
      const float w0 = wg[(size_t)(tb + 0) * NE + e];
      const float w1 = wg[(size_t)(tb + 1) * NE + e];
      const float w2 = wg[(size_t)(tb + 2) * NE + e];
      const float w3 = wg[(size_t)(tb + 3) * NE + e];
#pragma unroll
      for (int ni = 0; ni < 4; ++ni) {
        accO[mi][ni][0] += w0 * acc[mi][ni][0];
        accO[mi][ni][1] += w1 * acc[mi][ni][1];
        accO[mi][ni][2] += w2 * acc[mi][ni][2];
        accO[mi][ni][3] += w3 * acc[mi][ni][3];
      }
    }
  }

  // epilogue: gated bias + store (C/D: col = lane&15)
#pragma unroll
  for (int mi = 0; mi < 4; ++mi) {
    const int tb = row0 + wr * 64 + mi * 16 + lhi * 4;
#pragma unroll
    for (int j = 0; j < 4; ++j) {
      const int t = tb + j;
#pragma unroll
      for (int ni = 0; ni < 4; ++ni) {
        const int d = col0 + wc * 64 + ni * 16 + l15;
        float bias = 0.f;
#pragma unroll
        for (int e2 = 0; e2 < NE; ++e2)
          bias += wg[(size_t)t * NE + e2] * eb[(size_t)e2 * HD + d];
        out[(size_t)t * HD + d] = accO[mi][ni][j] + bias;
      }
    }
  }
}

extern "C" void kernel_launch(void* const* d_in, const int* in_sizes, int n_in,
                              void* d_out, int out_size, void* d_ws, size_t ws_size,
                              hipStream_t stream) {
  const float* x  = (const float*)d_in[0];   // [4,2048,1024]
  const float* gw = (const float*)d_in[1];   // [1024,8]
  const float* gb = (const float*)d_in[2];   // [8]
  const float* ew = (const float*)d_in[3];   // [8,1024,1024]
  const float* eb = (const float*)d_in[4];   // [8,1024]
  float* out = (float*)d_out;                // [4,2048,1024] fp32

  char* ws = (char*)d_ws;
  u16*   abf   = (u16*)ws;                               // 16 MB  bf16 x
  u16*   wt    = (u16*)(ws + (size_t)16 * 1024 * 1024);  // 16 MB  bf16 Wt
  float* wgate = (float*)(ws + (size_t)32 * 1024 * 1024);// 256 KB gate weights

  gate_conv_kernel<<<dim3(TTOK / 4), dim3(256), 0, stream>>>(x, gw, gb, wgate, abf);
  wconv_kernel<<<dim3(16, 16, 8), dim3(256), 0, stream>>>(ew, wt);
  moe_gemm_kernel<<<dim3((TTOK / BM) * (HD / BN)), dim3(256), 0, stream>>>(abf, wt, wgate, eb, out);
}